// Round 6
// baseline (42.286 us; speedup 1.0000x reference)
//
#include <hip/hip_runtime.h>

#define WSZ    64
#define BLOCK  256
#define STRIDE 20            // dwords per LDS row: 16 data + 4 pad (even bank spread, 16B-aligned)
#define INV2PI 0.15915494309189535f   // v_sin/v_cos take revolutions

__device__ __forceinline__ float rl(float v, int t) {
    return __builtin_bit_cast(float, __builtin_amdgcn_readlane(__builtin_bit_cast(int, v), t));
}

__global__ __launch_bounds__(BLOCK) void sq_main(
    const float* __restrict__ x,
    const float* __restrict__ theta,
    const float* __restrict__ w,
    const float* __restrict__ bias,
    float* __restrict__ out)
{
    // Per-wave private buffer: 64 rows x 20 dwords = 5120 B; 4 waves -> 20480 B/block
    // -> 8 blocks/CU = 32 waves/CU. No __syncthreads anywhere (waves fully independent).
    __shared__ float xs[4][WSZ * STRIDE];

    const int tid  = threadIdx.x;
    const int lane = tid & 63;
    const int wid  = tid >> 6;
    const size_t wrow0 = (size_t)blockIdx.x * BLOCK + wid * 64;
    const float* xw = x + wrow0 * WSZ;
    float* ws = xs[wid];

    // ---- step-t Bloch coefs of Rz(b)*Ry(a) live in lane t's VGPRs ----
    // M = [cb*ca, -sb, cb*sa; sb*ca, cb, sb*sa; -sa, 0, ca]
    float2 th = reinterpret_cast<const float2*>(theta)[lane];
    float sa = __builtin_amdgcn_sinf(th.x * INV2PI);
    float ca = __builtin_amdgcn_cosf(th.x * INV2PI);
    float sb = __builtin_amdgcn_sinf(th.y * INV2PI);
    float cb = __builtin_amdgcn_cosf(th.y * INV2PI);
    float m00 = cb * ca, m01 = -sb, m02 = cb * sa;
    float m10 = sb * ca, m11 = cb,  m12 = sb * sa;
    float m20 = -sa,     m22 = ca;

    // ---- chunked staging: 16 cols/chunk; load instr j covers rows j*16..j*16+15,
    // 64B contiguous per row (chunk c and c+1 share each 128B line back-to-back) ----
    const int lrow  = lane >> 2;   // 0..15
    const int lslot = lane & 3;    // float4 slot within the 16-col chunk

    float4 stage[4];
    #pragma unroll
    for (int j = 0; j < 4; ++j)
        stage[j] = *reinterpret_cast<const float4*>(
            xw + (size_t)(j * 16 + lrow) * WSZ + lslot * 4);

    float vx = 0.0f, vy = 0.0f, vz = 1.0f;

    #pragma unroll
    for (int c = 0; c < 4; ++c) {
        // store staged chunk c (ds_write_b128, even bank spread)
        #pragma unroll
        for (int j = 0; j < 4; ++j)
            *reinterpret_cast<float4*>(&ws[(j * 16 + lrow) * STRIDE + lslot * 4]) = stage[j];

        // prefetch chunk c+1; flies under this chunk's compute
        if (c < 3) {
            #pragma unroll
            for (int j = 0; j < 4; ++j)
                stage[j] = *reinterpret_cast<const float4*>(
                    xw + (size_t)(j * 16 + lrow) * WSZ + (c + 1) * 16 + lslot * 4);
        }

        // compute 16 steps; lane reads its own row (conflict-free b128, in-order RAW)
        #pragma unroll
        for (int c2 = 0; c2 < 4; ++c2) {
            float4 xv = *reinterpret_cast<const float4*>(&ws[lane * STRIDE + c2 * 4]);
            float xr[4] = {xv.x, xv.y, xv.z, xv.w};
            #pragma unroll
            for (int j = 0; j < 4; ++j) {
                const int t = c * 16 + c2 * 4 + j;   // compile-time step index
                float r  = xr[j] * INV2PI;
                float s  = __builtin_amdgcn_sinf(r);
                float co = __builtin_amdgcn_cosf(r);
                float y1 = co * vy - s * vz;         // Rx(x_t)
                float z1 = s  * vy + co * vz;
                float nx = rl(m00, t) * vx + rl(m01, t) * y1 + rl(m02, t) * z1;
                float ny = rl(m10, t) * vx + rl(m11, t) * y1 + rl(m12, t) * z1;
                float nz = rl(m20, t) * vx + rl(m22, t) * z1;   // m21 == 0
                vx = nx; vy = ny; vz = nz;
            }
        }
    }

    out[wrow0 + lane] = vz * w[0] + bias[0];
}

extern "C" void kernel_launch(void* const* d_in, const int* in_sizes, int n_in,
                              void* d_out, int out_size, void* d_ws, size_t ws_size,
                              hipStream_t stream) {
    const float* x     = (const float*)d_in[0];
    const float* theta = (const float*)d_in[1];
    const float* w     = (const float*)d_in[2];
    const float* b     = (const float*)d_in[3];
    float* out = (float*)d_out;

    int nrows = out_size;                 // B = 524288 (divisible by 256)
    int grid  = nrows / BLOCK;            // 2048 blocks
    sq_main<<<grid, BLOCK, 0, stream>>>(x, theta, w, b, out);
}